// Round 8
// baseline (434.057 us; speedup 1.0000x reference)
//
#include <hip/hip_runtime.h>
#include <hip/hip_fp16.h>

typedef _Float16 half8 __attribute__((ext_vector_type(8)));
typedef float f32x4 __attribute__((ext_vector_type(4)));

constexpr int M = 2048;    // B*S
constexpr int N = 10240;   // DOUT
constexpr int K = 4096;    // DIN

// ---------------------------------------------------------------------------
// Pre-pass 1: W fp32 -> fp16 * fp16(scale). Bit-identical to reference.
__global__ __launch_bounds__(256)
void dequant_w_kernel(const float* __restrict__ W, const float* __restrict__ Wsc,
                      _Float16* __restrict__ Wh) {
    const long total = (long)N * K / 8;
    for (long i = (long)blockIdx.x * blockDim.x + threadIdx.x; i < total;
         i += (long)gridDim.x * blockDim.x) {
        const long base = i * 8;
        const int row = (int)(base >> 12);           // / K
        const _Float16 s = (_Float16)Wsc[row];
        const float4 w0 = ((const float4*)(W + base))[0];
        const float4 w1 = ((const float4*)(W + base))[1];
        half8 h;
        h[0] = (_Float16)w0.x * s; h[1] = (_Float16)w0.y * s;
        h[2] = (_Float16)w0.z * s; h[3] = (_Float16)w0.w * s;
        h[4] = (_Float16)w1.x * s; h[5] = (_Float16)w1.y * s;
        h[6] = (_Float16)w1.z * s; h[7] = (_Float16)w1.w * s;
        *(half8*)(Wh + base) = h;
    }
}

// Pre-pass 2: A fp32 (fp16-valued) -> fp16 (exact).
__global__ __launch_bounds__(256)
void convert_a_kernel(const float* __restrict__ A, _Float16* __restrict__ Ah) {
    const long total = (long)M * K / 8;
    for (long i = (long)blockIdx.x * blockDim.x + threadIdx.x; i < total;
         i += (long)gridDim.x * blockDim.x) {
        const long base = i * 8;
        const float4 a0 = ((const float4*)(A + base))[0];
        const float4 a1 = ((const float4*)(A + base))[1];
        half8 h;
        h[0] = (_Float16)a0.x; h[1] = (_Float16)a0.y;
        h[2] = (_Float16)a0.z; h[3] = (_Float16)a0.w;
        h[4] = (_Float16)a1.x; h[5] = (_Float16)a1.y;
        h[6] = (_Float16)a1.z; h[7] = (_Float16)a1.w;
        *(half8*)(Ah + base) = h;
    }
}

// ---------------------------------------------------------------------------
// 256x320 GEMM: 8x32 = 256 blocks = EXACTLY 1 scheduling round (no tail).
// 8 waves (2M x 4N) of 128x80 each -> 49.2 FLOP per LDS byte (MFMA-dominant):
// per CU-tile MFMA 3106 cy vs LDS reads ~1900 cy. acc[8][5] (AGPR file).
// Schedule = round-7's 2-barrier: all 26 ds_reads front-loaded (g1's 18
// first), g1 (40 MFMA) overlaps af[4..7] drain; stage t+2 (9 loads) after
// BAR1 overlaps register-only g2; counted vmcnt(9) (never 0 mid-loop).
// T2 swizzle: linear gload_lds dest + pre-swizzled src col + swizzled read.
//
// Lifetime ledger: all reads of tile t issued in P0, LGKM0 before BAR1 ->
// after BAR1 every wave's reads of BOTH regions complete -> staging t+2
// into cur is safe. g2 is register-only. vmcnt(9) at tile end: outstanding
// = t+2's 9 + t+1's 9 -> waits t+1's, leaves t+2's in flight. BAR2
// publishes t+1.
constexpr int BM = 256, BN = 320, BK = 64;
constexpr int AELE = BM * BK;   // 16384 fp16 = 32 KB
constexpr int BELE = BN * BK;   // 20480 fp16 = 40 KB
constexpr int NT = K / BK;      // 64 K-tiles

#define BAR()   asm volatile("s_barrier" ::: "memory")
#define LGKM0() asm volatile("s_waitcnt lgkmcnt(0)" ::: "memory")

__device__ __forceinline__ half8 lds_rd(const _Float16* base, int row, int eo) {
    // T2: physical 16B slot = slot ^ (row&7)
    const int ps = (eo >> 3) ^ (row & 7);
    return *(const half8*)(base + row * BK + ps * 8);
}

__global__ __launch_bounds__(512, 1)
void qgemm256x320_kernel(const _Float16* __restrict__ Ag,  // [M,K] fp16 (ws)
                         const _Float16* __restrict__ Wg,  // [N,K] fp16 dequant
                         const float*    __restrict__ bias,
                         float*          __restrict__ C)
{
    __shared__ _Float16 AsF[2 * AELE];   // 64 KB
    __shared__ _Float16 BsF[2 * BELE];   // 80 KB   (144 KB total)

    // XCD-bijective swizzle: 256 = 8 XCD x 32; within a chunk brow-fast ->
    // 8-block runs share one 2.6MB B panel; lockstep K-walk keeps the
    // per-K working set (8 A-slabs + 4 B-slabs ~ 416 KB) L2-resident.
    const int orig = blockIdx.x;
    const int wgid = (orig & 7) * 32 + (orig >> 3);
    const int m0 = (wgid & 7) * BM;
    const int n0 = (wgid >> 3) * BN;

    const int tid  = threadIdx.x;
    const int lane = tid & 63;
    const int w    = tid >> 6;
    const int wm   = w >> 2;            // 0..1 -> rows wm*128
    const int wn   = w & 3;             // 0..3 -> cols wn*80
    const int fr   = lane & 15;
    const int fkE  = (lane >> 4) * 8;

    const int trow  = tid >> 3;                        // staging row 0..63
    const int swcol = (((tid & 7) ^ (trow & 7))) * 8;  // pre-swizzled src col

    // stage unit = 64 rows x 64 cols fp16 = 8 KB = 512 thr x 16 B
    auto stage_a = [&](int b, int u, int kcol) {
        const _Float16* src = Ag + (size_t)(m0 + u * 64 + trow) * K + (kcol + swcol);
        __builtin_amdgcn_global_load_lds(
            (const __attribute__((address_space(1))) void*)src,
            (__attribute__((address_space(3))) void*)(AsF + b * AELE + u * 4096 + tid * 8),
            16, 0, 0);
    };
    auto stage_b = [&](int b, int u, int kcol) {
        const _Float16* src = Wg + (size_t)(n0 + u * 64 + trow) * K + (kcol + swcol);
        __builtin_amdgcn_global_load_lds(
            (const __attribute__((address_space(1))) void*)src,
            (__attribute__((address_space(3))) void*)(BsF + b * BELE + u * 4096 + tid * 8),
            16, 0, 0);
    };

    f32x4 acc[8][5];
#pragma unroll
    for (int i = 0; i < 8; ++i)
#pragma unroll
        for (int j = 0; j < 5; ++j)
            acc[i][j] = (f32x4){0.f, 0.f, 0.f, 0.f};

    // prologue: tile0 -> buf0 (9 loads), tile1 -> buf1 (9 loads)
#pragma unroll
    for (int u = 0; u < 4; ++u) stage_a(0, u, 0);
#pragma unroll
    for (int u = 0; u < 5; ++u) stage_b(0, u, 0);
#pragma unroll
    for (int u = 0; u < 4; ++u) stage_a(1, u, BK);
#pragma unroll
    for (int u = 0; u < 5; ++u) stage_b(1, u, BK);
    asm volatile("s_waitcnt vmcnt(9)" ::: "memory");   // tile0 landed
    BAR();

#pragma unroll 1
    for (int t = 0; t < NT; ++t) {
        const int cur = t & 1;
        const _Float16* Ab = AsF + cur * AELE;
        const _Float16* Bb = BsF + cur * BELE;
        const bool pf2 = (t + 2 < NT);
        const int k2 = (t + 2) * BK;

        half8 af[8][2], bf[5][2];

        // ---- P0: reads ordered so g1's operands (af[0..3], bf) finish first
#pragma unroll
        for (int rb = 0; rb < 4; ++rb)
#pragma unroll
            for (int kh = 0; kh < 2; ++kh)
                af[rb][kh] = lds_rd(Ab, wm * 128 + rb * 16 + fr, kh * 32 + fkE);
#pragma unroll
        for (int cb = 0; cb < 5; ++cb)
#pragma unroll
            for (int kh = 0; kh < 2; ++kh)
                bf[cb][kh] = lds_rd(Bb, wn * 80 + cb * 16 + fr, kh * 32 + fkE);
#pragma unroll
        for (int rb = 4; rb < 8; ++rb)
#pragma unroll
            for (int kh = 0; kh < 2; ++kh)
                af[rb][kh] = lds_rd(Ab, wm * 128 + rb * 16 + fr, kh * 32 + fkE);

        // MFMA g1: rows 0..3 x all 5 col-blocks (40 MFMA); af[4..7] reads
        // drain under it via compiler counted lgkm waits.
        __builtin_amdgcn_s_setprio(1);
#pragma unroll
        for (int rb = 0; rb < 4; ++rb)
#pragma unroll
            for (int cb = 0; cb < 5; ++cb)
#pragma unroll
                for (int kh = 0; kh < 2; ++kh)
                    acc[rb][cb] = __builtin_amdgcn_mfma_f32_16x16x32_f16(
                        af[rb][kh], bf[cb][kh], acc[rb][cb], 0, 0, 0);
        __builtin_amdgcn_s_setprio(0);

        LGKM0();   // all own reads complete (cross-wave safety for staging)
        BAR();     // -> every wave's reads of A(cur)+B(cur) are done

        // ---- P1: stage tile t+2 into cur (regions free); MFMA g2 (reg-only)
        if (pf2) {
#pragma unroll
            for (int u = 0; u < 4; ++u) stage_a(cur, u, k2);
#pragma unroll
            for (int u = 0; u < 5; ++u) stage_b(cur, u, k2);
        }
        __builtin_amdgcn_s_setprio(1);
#pragma unroll
        for (int rb = 4; rb < 8; ++rb)
#pragma unroll
            for (int cb = 0; cb < 5; ++cb)
#pragma unroll
                for (int kh = 0; kh < 2; ++kh)
                    acc[rb][cb] = __builtin_amdgcn_mfma_f32_16x16x32_f16(
                        af[rb][kh], bf[cb][kh], acc[rb][cb], 0, 0, 0);
        __builtin_amdgcn_s_setprio(0);

        if (pf2) asm volatile("s_waitcnt vmcnt(9)" ::: "memory");  // t+1 landed
        else     asm volatile("s_waitcnt vmcnt(0)" ::: "memory");  // tail drain
        BAR();   // publish t+1
    }

    // epilogue: C/D layout col = lane&15, row = (lane>>4)*4 + reg
    float bb[5];
#pragma unroll
    for (int j = 0; j < 5; ++j)
        bb[j] = bias[n0 + wn * 80 + j * 16 + fr];
#pragma unroll
    for (int i = 0; i < 8; ++i) {
        const int row = m0 + wm * 128 + i * 16 + (lane >> 4) * 4;
#pragma unroll
        for (int j = 0; j < 5; ++j) {
            const int col = n0 + wn * 80 + j * 16 + fr;
#pragma unroll
            for (int r = 0; r < 4; ++r)
                C[(size_t)(row + r) * N + col] =
                    (float)(_Float16)(acc[i][j][r] + bb[j]);
        }
    }
}

// ---------------------------------------------------------------------------
// Fallback (round-2 fused kernel, passing @434us) if ws too small.
__global__ __launch_bounds__(256, 2)
void qlinear_fused_kernel(const float* __restrict__ A, const float* __restrict__ W,
                          const float* __restrict__ Wsc, const float* __restrict__ bias,
                          float* __restrict__ C)
{
    __shared__ _Float16 As[128][64];
    __shared__ _Float16 Bs[128][64];

    const int nwg  = (M / 128) * (N / 128);
    const int orig = blockIdx.x;
    const int wgid = (orig & 7) * (nwg >> 3) + (orig >> 3);
    const int brow = wgid & (M / 128 - 1);
    const int bcol = wgid / (M / 128);
    const int m0 = brow * 128;
    const int n0 = bcol * 128;

    const int t    = threadIdx.x;
    const int lane = t & 63;
    const int wave = t >> 6;
    const int wr = (wave >> 1) * 64;
    const int wc = (wave & 1) * 64;
    const int fr = lane & 15;
    const int fk = (lane >> 4) * 8;
    const int srow = t >> 3;
    const int scol = (t & 7) * 8;

    _Float16 hs[4];
#pragma unroll
    for (int p = 0; p < 4; ++p)
        hs[p] = (_Float16)Wsc[n0 + srow + p * 32];

    f32x4 acc[4][4];
#pragma unroll
    for (int i = 0; i < 4; ++i)
#pragma unroll
        for (int j = 0; j < 4; ++j)
            acc[i][j] = (f32x4){0.f, 0.f, 0.f, 0.f};

    for (int k0 = 0; k0 < K; k0 += 64) {
        __syncthreads();
#pragma unroll
        for (int c = 0; c < 4; ++c) {
            const int rl = c * 32 + srow;
            const float* asrc = A + (size_t)(m0 + rl) * K + (k0 + scol);
            const float4 a0 = ((const float4*)asrc)[0];
            const float4 a1 = ((const float4*)asrc)[1];
            half8 av;
            av[0] = (_Float16)a0.x; av[1] = (_Float16)a0.y;
            av[2] = (_Float16)a0.z; av[3] = (_Float16)a0.w;
            av[4] = (_Float16)a1.x; av[5] = (_Float16)a1.y;
            av[6] = (_Float16)a1.z; av[7] = (_Float16)a1.w;
            *(half8*)&As[rl][scol] = av;
        }
#pragma unroll
        for (int p = 0; p < 4; ++p) {
            const int nl = srow + p * 32;
            const float* wsrc = W + (size_t)(n0 + nl) * K + (k0 + scol);
            const float4 w0 = ((const float4*)wsrc)[0];
            const float4 w1 = ((const float4*)wsrc)[1];
            half8 hv;
            hv[0] = (_Float16)w0.x * hs[p]; hv[1] = (_Float16)w0.y * hs[p];
            hv[2] = (_Float16)w0.z * hs[p]; hv[3] = (_Float16)w0.w * hs[p];
            hv[4] = (_Float16)w1.x * hs[p]; hv[5] = (_Float16)w1.y * hs[p];
            hv[6] = (_Float16)w1.z * hs[p]; hv[7] = (_Float16)w1.w * hs[p];
            *(half8*)&Bs[nl][scol] = hv;
        }
        __syncthreads();
#pragma unroll
        for (int kk = 0; kk < 64; kk += 32) {
            half8 av[4], bv[4];
#pragma unroll
            for (int i = 0; i < 4; ++i)
                av[i] = *(const half8*)&As[wr + i * 16 + fr][kk + fk];
#pragma unroll
            for (int j = 0; j < 4; ++j)
                bv[j] = *(const half8*)&Bs[wc + j * 16 + fr][kk + fk];
#pragma unroll
            for (int i = 0; i < 4; ++i)
#pragma unroll
                for (int j = 0; j < 4; ++j)
                    acc[i][j] = __builtin_amdgcn_mfma_f32_16x16x32_f16(
                        av[i], bv[j], acc[i][j], 0, 0, 0);
        }
    }
#pragma unroll
    for (int i = 0; i < 4; ++i) {
        const int row = m0 + wr + i * 16 + (lane >> 4) * 4;
#pragma unroll
        for (int j = 0; j < 4; ++j) {
            const int col = n0 + wc + j * 16 + fr;
            const float bbf = bias[col];
#pragma unroll
            for (int r = 0; r < 4; ++r)
                C[(size_t)(row + r) * N + col] =
                    (float)(_Float16)(acc[i][j][r] + bbf);
        }
    }
}

extern "C" void kernel_launch(void* const* d_in, const int* in_sizes, int n_in,
                              void* d_out, int out_size, void* d_ws, size_t ws_size,
                              hipStream_t stream) {
    const float* A    = (const float*)d_in[0];
    const float* W    = (const float*)d_in[1];
    const float* Wsc  = (const float*)d_in[2];
    const float* bias = (const float*)d_in[3];
    float* C = (float*)d_out;

    const size_t a_bytes = (size_t)M * K * sizeof(_Float16);   // 16.78 MB
    const size_t w_bytes = (size_t)N * K * sizeof(_Float16);   // 83.89 MB

    if (ws_size >= a_bytes + w_bytes) {
        _Float16* Ah = (_Float16*)d_ws;
        _Float16* Wh = (_Float16*)((char*)d_ws + a_bytes);
        convert_a_kernel<<<dim3(1024), dim3(256), 0, stream>>>(A, Ah);
        dequant_w_kernel<<<dim3(2048), dim3(256), 0, stream>>>(W, Wsc, Wh);
        const int nwg = (M / BM) * (N / BN);  // 256
        qgemm256x320_kernel<<<dim3(nwg), dim3(512), 0, stream>>>(Ah, Wh, bias, C);
    } else {
        const int nwg = (M / 128) * (N / 128);
        qlinear_fused_kernel<<<dim3(nwg), dim3(256), 0, stream>>>(A, W, Wsc, bias, C);
    }
}

// Round 9
// 374.200 us; speedup vs baseline: 1.1600x; 1.1600x over previous
//
#include <hip/hip_runtime.h>
#include <hip/hip_fp16.h>

typedef _Float16 half8 __attribute__((ext_vector_type(8)));
typedef float f32x4 __attribute__((ext_vector_type(4)));

constexpr int M = 2048;    // B*S
constexpr int N = 10240;   // DOUT
constexpr int K = 4096;    // DIN

// ---------------------------------------------------------------------------
// Pre-pass 1: W fp32 -> fp16 * fp16(scale). Bit-identical to reference.
__global__ __launch_bounds__(256)
void dequant_w_kernel(const float* __restrict__ W, const float* __restrict__ Wsc,
                      _Float16* __restrict__ Wh) {
    const long total = (long)N * K / 8;
    for (long i = (long)blockIdx.x * blockDim.x + threadIdx.x; i < total;
         i += (long)gridDim.x * blockDim.x) {
        const long base = i * 8;
        const int row = (int)(base >> 12);           // / K
        const _Float16 s = (_Float16)Wsc[row];
        const float4 w0 = ((const float4*)(W + base))[0];
        const float4 w1 = ((const float4*)(W + base))[1];
        half8 h;
        h[0] = (_Float16)w0.x * s; h[1] = (_Float16)w0.y * s;
        h[2] = (_Float16)w0.z * s; h[3] = (_Float16)w0.w * s;
        h[4] = (_Float16)w1.x * s; h[5] = (_Float16)w1.y * s;
        h[6] = (_Float16)w1.z * s; h[7] = (_Float16)w1.w * s;
        *(half8*)(Wh + base) = h;
    }
}

// Pre-pass 2: A fp32 (fp16-valued) -> fp16 (exact).
__global__ __launch_bounds__(256)
void convert_a_kernel(const float* __restrict__ A, _Float16* __restrict__ Ah) {
    const long total = (long)M * K / 8;
    for (long i = (long)blockIdx.x * blockDim.x + threadIdx.x; i < total;
         i += (long)gridDim.x * blockDim.x) {
        const long base = i * 8;
        const float4 a0 = ((const float4*)(A + base))[0];
        const float4 a1 = ((const float4*)(A + base))[1];
        half8 h;
        h[0] = (_Float16)a0.x; h[1] = (_Float16)a0.y;
        h[2] = (_Float16)a0.z; h[3] = (_Float16)a0.w;
        h[4] = (_Float16)a1.x; h[5] = (_Float16)a1.y;
        h[6] = (_Float16)a1.z; h[7] = (_Float16)a1.w;
        *(half8*)(Ah + base) = h;
    }
}

// ---------------------------------------------------------------------------
// B-streaming GEMM (AITER flatmm pattern): B direct global->register (L2-
// resident panel), A via reg-staged LDS dbuf (T14 split). 128x320 tile,
// 8 waves (2M x 4N) of 64x80, grid 512 = exactly 2 rounds.
//
// Per-CU-tile: LDS reads 64 KB + writes 16 KB = 941 cy < MFMA 1553 cy ->
// MFMA-bound. B reloads interleave into the MFMA cluster cb-major; WAR
// deps on bf registers pin each reload after its consuming MFMAs.
// ALL waitcnts are compiler-derived (no hand-counted vmcnt):
//   - bf(t) use: compiler waits exactly the loads younger than bf(t).
//   - ds_write of areg: compiler waits exactly the B loads younger than areg.
// Barrier ledger (2/tile): LGKM0+BAR1 = all waves' A(cur) ds_reads done ->
// ds_write A(t+1) into nxt safe (t-1's nxt readers drained at t-1's BAR1).
// LGKM0+BAR2 publishes A(t+1).
constexpr int BM = 128, BN = 320, BK = 64;
constexpr int AELE = BM * BK;   // 8192 fp16 = 16 KB
constexpr int NT = K / BK;      // 64 K-tiles

#define BAR()   asm volatile("s_barrier" ::: "memory")
#define LGKM0() asm volatile("s_waitcnt lgkmcnt(0)" ::: "memory")

__device__ __forceinline__ half8 lds_rd(const _Float16* base, int row, int eo) {
    // T2: physical 16B slot = slot ^ (row&7)
    const int ps = (eo >> 3) ^ (row & 7);
    return *(const half8*)(base + row * BK + ps * 8);
}

__global__ __launch_bounds__(512, 2)
void qgemm_bstream_kernel(const _Float16* __restrict__ Ag,  // [M,K] fp16 (ws)
                          const _Float16* __restrict__ Wg,  // [N,K] fp16 dequant
                          const float*    __restrict__ bias,
                          float*          __restrict__ C)
{
    __shared__ _Float16 AsF[2 * AELE];   // 32 KB total

    // XCD-bijective swizzle: 512 = 8 chunks x 64; brow-fast -> 16-block runs
    // share one 2.6MB B panel (L2-resident per XCD; B streamed from L2).
    const int orig = blockIdx.x;
    const int wgid = (orig & 7) * 64 + (orig >> 3);
    const int m0 = (wgid & 15) * BM;
    const int n0 = (wgid >> 4) * BN;

    const int tid  = threadIdx.x;
    const int lane = tid & 63;
    const int w    = tid >> 6;
    const int wm   = w >> 2;            // 0..1 -> rows wm*64
    const int wn   = w & 3;             // 0..3 -> cols wn*80
    const int fr   = lane & 15;
    const int fkE  = (lane >> 4) * 8;

    // A reg-stage mapping: thread covers 32 B = 2 slots of row (tid>>2).
    const int arow   = tid >> 2;        // 0..127
    const int aslot0 = (tid & 3) * 2;   // 0,2,4,6
    const int acol   = aslot0 * 8;      // 0,16,32,48

    // B fragment bases (per cb, fkE folded in). cb static-indexed everywhere.
    const _Float16* bsrc[5];
#pragma unroll
    for (int cb = 0; cb < 5; ++cb)
        bsrc[cb] = Wg + (size_t)(n0 + wn * 80 + cb * 16 + fr) * K + fkE;

    f32x4 acc[4][5];
#pragma unroll
    for (int i = 0; i < 4; ++i)
#pragma unroll
        for (int j = 0; j < 5; ++j)
            acc[i][j] = (f32x4){0.f, 0.f, 0.f, 0.f};

    // ---- prologue: A(0) -> regs -> LDS buf0; B(0) -> bf
    const _Float16* a_src = Ag + (size_t)(m0 + arow) * K + acol;
    half8 ar0 = *(const half8*)(a_src);
    half8 ar1 = *(const half8*)(a_src + 8);
    half8 bf[5][2];
#pragma unroll
    for (int cb = 0; cb < 5; ++cb)
#pragma unroll
        for (int kh = 0; kh < 2; ++kh)
            bf[cb][kh] = *(const half8*)(bsrc[cb] + kh * 32);
    {
        _Float16* wdst = AsF + arow * BK;   // buf0 (compiler waits ar0/ar1)
        *(half8*)(wdst + ((aslot0)     ^ (arow & 7)) * 8) = ar0;
        *(half8*)(wdst + ((aslot0 + 1) ^ (arow & 7)) * 8) = ar1;
    }
    LGKM0(); BAR();

#pragma unroll 1
    for (int t = 0; t < NT; ++t) {
        const int cur = t & 1, nxt = cur ^ 1;
        const _Float16* Ab = AsF + cur * AELE;
        const bool pf = (t + 1 < NT);
        const int k1 = (t + 1) * BK;

        // (a) ds_read A fragments of tile t
        half8 af[4][2];
#pragma unroll
        for (int rb = 0; rb < 4; ++rb)
#pragma unroll
            for (int kh = 0; kh < 2; ++kh)
                af[rb][kh] = lds_rd(Ab, wm * 64 + rb * 16 + fr, kh * 32 + fkE);

        // (b) issue A(t+1) global loads (consumed by ds_write after BAR1;
        //     latency hidden under the MFMA cluster)
        if (pf) {
            const _Float16* s = Ag + (size_t)(m0 + arow) * K + k1 + acol;
            ar0 = *(const half8*)(s);
            ar1 = *(const half8*)(s + 8);
        }

        // (c) MFMA cluster, cb-major; B(t+1) reload for cb follows its
        //     consumers (WAR on bf[cb] enforces the AITER-style interleave)
        __builtin_amdgcn_s_setprio(1);
#pragma unroll
        for (int cb = 0; cb < 5; ++cb) {
#pragma unroll
            for (int rb = 0; rb < 4; ++rb)
#pragma unroll
                for (int kh = 0; kh < 2; ++kh)
                    acc[rb][cb] = __builtin_amdgcn_mfma_f32_16x16x32_f16(
                        af[rb][kh], bf[cb][kh], acc[rb][cb], 0, 0, 0);
            if (pf) {
#pragma unroll
                for (int kh = 0; kh < 2; ++kh)
                    bf[cb][kh] = *(const half8*)(bsrc[cb] + k1 + kh * 32);
            }
        }
        __builtin_amdgcn_s_setprio(0);

        // (d) all waves' reads of A(cur) done
        LGKM0(); BAR();

        // (e) ds_write A(t+1) -> nxt (compiler waits ar0/ar1, leaves B loads
        //     in flight: they are younger than the A loads)
        if (pf) {
            _Float16* wdst = AsF + nxt * AELE + arow * BK;
            *(half8*)(wdst + ((aslot0)     ^ (arow & 7)) * 8) = ar0;
            *(half8*)(wdst + ((aslot0 + 1) ^ (arow & 7)) * 8) = ar1;
        }

        // (f) publish A(t+1)
        LGKM0(); BAR();
    }

    // epilogue: C/D layout col = lane&15, row = (lane>>4)*4 + reg
    float bb[5];
#pragma unroll
    for (int j = 0; j < 5; ++j)
        bb[j] = bias[n0 + wn * 80 + j * 16 + fr];
#pragma unroll
    for (int i = 0; i < 4; ++i) {
        const int row = m0 + wm * 64 + i * 16 + (lane >> 4) * 4;
#pragma unroll
        for (int j = 0; j < 5; ++j) {
            const int col = n0 + wn * 80 + j * 16 + fr;
#pragma unroll
            for (int r = 0; r < 4; ++r)
                C[(size_t)(row + r) * N + col] =
                    (float)(_Float16)(acc[i][j][r] + bb[j]);
        }
    }
}

// ---------------------------------------------------------------------------
// Fallback (round-2 fused kernel, passing @434us) if ws too small.
__global__ __launch_bounds__(256, 2)
void qlinear_fused_kernel(const float* __restrict__ A, const float* __restrict__ W,
                          const float* __restrict__ Wsc, const float* __restrict__ bias,
                          float* __restrict__ C)
{
    __shared__ _Float16 As[128][64];
    __shared__ _Float16 Bs[128][64];

    const int nwg  = (M / 128) * (N / 128);
    const int orig = blockIdx.x;
    const int wgid = (orig & 7) * (nwg >> 3) + (orig >> 3);
    const int brow = wgid & (M / 128 - 1);
    const int bcol = wgid / (M / 128);
    const int m0 = brow * 128;
    const int n0 = bcol * 128;

    const int t    = threadIdx.x;
    const int lane = t & 63;
    const int wave = t >> 6;
    const int wr = (wave >> 1) * 64;
    const int wc = (wave & 1) * 64;
    const int fr = lane & 15;
    const int fk = (lane >> 4) * 8;
    const int srow = t >> 3;
    const int scol = (t & 7) * 8;

    _Float16 hs[4];
#pragma unroll
    for (int p = 0; p < 4; ++p)
        hs[p] = (_Float16)Wsc[n0 + srow + p * 32];

    f32x4 acc[4][4];
#pragma unroll
    for (int i = 0; i < 4; ++i)
#pragma unroll
        for (int j = 0; j < 4; ++j)
            acc[i][j] = (f32x4){0.f, 0.f, 0.f, 0.f};

    for (int k0 = 0; k0 < K; k0 += 64) {
        __syncthreads();
#pragma unroll
        for (int c = 0; c < 4; ++c) {
            const int rl = c * 32 + srow;
            const float* asrc = A + (size_t)(m0 + rl) * K + (k0 + scol);
            const float4 a0 = ((const float4*)asrc)[0];
            const float4 a1 = ((const float4*)asrc)[1];
            half8 av;
            av[0] = (_Float16)a0.x; av[1] = (_Float16)a0.y;
            av[2] = (_Float16)a0.z; av[3] = (_Float16)a0.w;
            av[4] = (_Float16)a1.x; av[5] = (_Float16)a1.y;
            av[6] = (_Float16)a1.z; av[7] = (_Float16)a1.w;
            *(half8*)&As[rl][scol] = av;
        }
#pragma unroll
        for (int p = 0; p < 4; ++p) {
            const int nl = srow + p * 32;
            const float* wsrc = W + (size_t)(n0 + nl) * K + (k0 + scol);
            const float4 w0 = ((const float4*)wsrc)[0];
            const float4 w1 = ((const float4*)wsrc)[1];
            half8 hv;
            hv[0] = (_Float16)w0.x * hs[p]; hv[1] = (_Float16)w0.y * hs[p];
            hv[2] = (_Float16)w0.z * hs[p]; hv[3] = (_Float16)w0.w * hs[p];
            hv[4] = (_Float16)w1.x * hs[p]; hv[5] = (_Float16)w1.y * hs[p];
            hv[6] = (_Float16)w1.z * hs[p]; hv[7] = (_Float16)w1.w * hs[p];
            *(half8*)&Bs[nl][scol] = hv;
        }
        __syncthreads();
#pragma unroll
        for (int kk = 0; kk < 64; kk += 32) {
            half8 av[4], bv[4];
#pragma unroll
            for (int i = 0; i < 4; ++i)
                av[i] = *(const half8*)&As[wr + i * 16 + fr][kk + fk];
#pragma unroll
            for (int j = 0; j < 4; ++j)
                bv[j] = *(const half8*)&Bs[wc + j * 16 + fr][kk + fk];
#pragma unroll
            for (int i = 0; i < 4; ++i)
#pragma unroll
                for (int j = 0; j < 4; ++j)
                    acc[i][j] = __builtin_amdgcn_mfma_f32_16x16x32_f16(
                        av[i], bv[j], acc[i][j], 0, 0, 0);
        }
    }
#pragma unroll
    for (int i = 0; i < 4; ++i) {
        const int row = m0 + wr + i * 16 + (lane >> 4) * 4;
#pragma unroll
        for (int j = 0; j < 4; ++j) {
            const int col = n0 + wc + j * 16 + fr;
            const float bbf = bias[col];
#pragma unroll
            for (int r = 0; r < 4; ++r)
                C[(size_t)(row + r) * N + col] =
                    (float)(_Float16)(acc[i][j][r] + bbf);
        }
    }
}

extern "C" void kernel_launch(void* const* d_in, const int* in_sizes, int n_in,
                              void* d_out, int out_size, void* d_ws, size_t ws_size,
                              hipStream_t stream) {
    const float* A    = (const float*)d_in[0];
    const float* W    = (const float*)d_in[1];
    const float* Wsc  = (const float*)d_in[2];
    const float* bias = (const float*)d_in[3];
    float* C = (float*)d_out;

    const size_t a_bytes = (size_t)M * K * sizeof(_Float16);   // 16.78 MB
    const size_t w_bytes = (size_t)N * K * sizeof(_Float16);   // 83.89 MB

    if (ws_size >= a_bytes + w_bytes) {
        _Float16* Ah = (_Float16*)d_ws;
        _Float16* Wh = (_Float16*)((char*)d_ws + a_bytes);
        convert_a_kernel<<<dim3(1024), dim3(256), 0, stream>>>(A, Ah);
        dequant_w_kernel<<<dim3(2048), dim3(256), 0, stream>>>(W, Wsc, Wh);
        const int nwg = (M / BM) * (N / BN);  // 512
        qgemm_bstream_kernel<<<dim3(nwg), dim3(512), 0, stream>>>(Ah, Wh, bias, C);
    } else {
        const int nwg = (M / 128) * (N / 128);
        qlinear_fused_kernel<<<dim3(nwg), dim3(256), 0, stream>>>(A, W, Wsc, bias, C);
    }
}

// Round 10
// 217.903 us; speedup vs baseline: 1.9920x; 1.7173x over previous
//
#include <hip/hip_runtime.h>
#include <hip/hip_fp16.h>

typedef _Float16 half8 __attribute__((ext_vector_type(8)));
typedef float f32x4 __attribute__((ext_vector_type(4)));

constexpr int M = 2048;    // B*S
constexpr int N = 10240;   // DOUT
constexpr int K = 4096;    // DIN

// ---------------------------------------------------------------------------
// Pre-pass 1: W fp32 -> fp16 * fp16(scale). Bit-identical to reference.
__global__ __launch_bounds__(256)
void dequant_w_kernel(const float* __restrict__ W, const float* __restrict__ Wsc,
                      _Float16* __restrict__ Wh) {
    const long total = (long)N * K / 8;
    for (long i = (long)blockIdx.x * blockDim.x + threadIdx.x; i < total;
         i += (long)gridDim.x * blockDim.x) {
        const long base = i * 8;
        const int row = (int)(base >> 12);           // / K
        const _Float16 s = (_Float16)Wsc[row];
        const float4 w0 = ((const float4*)(W + base))[0];
        const float4 w1 = ((const float4*)(W + base))[1];
        half8 h;
        h[0] = (_Float16)w0.x * s; h[1] = (_Float16)w0.y * s;
        h[2] = (_Float16)w0.z * s; h[3] = (_Float16)w0.w * s;
        h[4] = (_Float16)w1.x * s; h[5] = (_Float16)w1.y * s;
        h[6] = (_Float16)w1.z * s; h[7] = (_Float16)w1.w * s;
        *(half8*)(Wh + base) = h;
    }
}

// Pre-pass 2: A fp32 (fp16-valued) -> fp16 (exact).
__global__ __launch_bounds__(256)
void convert_a_kernel(const float* __restrict__ A, _Float16* __restrict__ Ah) {
    const long total = (long)M * K / 8;
    for (long i = (long)blockIdx.x * blockDim.x + threadIdx.x; i < total;
         i += (long)gridDim.x * blockDim.x) {
        const long base = i * 8;
        const float4 a0 = ((const float4*)(A + base))[0];
        const float4 a1 = ((const float4*)(A + base))[1];
        half8 h;
        h[0] = (_Float16)a0.x; h[1] = (_Float16)a0.y;
        h[2] = (_Float16)a0.z; h[3] = (_Float16)a0.w;
        h[4] = (_Float16)a1.x; h[5] = (_Float16)a1.y;
        h[6] = (_Float16)a1.z; h[7] = (_Float16)a1.w;
        *(half8*)(Ah + base) = h;
    }
}

// ---------------------------------------------------------------------------
// 128x160 GEMM, 4 waves (2M x 2N) of 64x80 — round-7 schedule, halved block:
// LDS dbuf 72 KB -> TWO co-resident blocks per CU (m97 implicit-overlap:
// one block's MFMAs run during the other's barrier/vmcnt windows).
// Grid 16x64 = 1024 = 256 CU x 2 co-res x 2 rounds, zero tail.
// T2 swizzle: linear gload_lds dest + pre-swizzled src col + swizzled read.
// T3+T4: distance-2 prefetch, counted vmcnt(9), never 0 mid-loop.
//
// Lifetime ledger (unchanged from round 7): all 18 ds_reads of tile t
// issued in P0; LGKM0 before BAR1 -> after BAR1 every wave's reads of BOTH
// regions complete -> staging t+2 into cur is safe. g2 is register-only.
// vmcnt(9) at tile end: outstanding = t+2's 9 + t+1's 9 -> waits t+1's,
// leaves t+2's in flight. BAR2 publishes t+1.
constexpr int BM = 128, BN = 160, BK = 64;
constexpr int AELE = BM * BK;   // 8192  fp16 = 16 KB
constexpr int BELE = BN * BK;   // 10240 fp16 = 20 KB
constexpr int NT = K / BK;      // 64 K-tiles

#define BAR()   asm volatile("s_barrier" ::: "memory")
#define LGKM0() asm volatile("s_waitcnt lgkmcnt(0)" ::: "memory")

__device__ __forceinline__ half8 lds_rd(const _Float16* base, int row, int eo) {
    // T2: physical 16B slot = slot ^ (row&7)
    const int ps = (eo >> 3) ^ (row & 7);
    return *(const half8*)(base + row * BK + ps * 8);
}

__global__ __launch_bounds__(256, 2)
void qgemm128x160_kernel(const _Float16* __restrict__ Ag,  // [M,K] fp16 (ws)
                         const _Float16* __restrict__ Wg,  // [N,K] fp16 dequant
                         const float*    __restrict__ bias,
                         float*          __restrict__ C)
{
    __shared__ _Float16 AsF[2 * AELE];   // 32 KB
    __shared__ _Float16 BsF[2 * BELE];   // 40 KB   (72 KB total)

    // XCD-bijective swizzle: 1024 = 8 chunks x 128; brow-fast -> 16-block
    // runs share one 1.3MB B panel (L2-resident per XCD).
    const int orig = blockIdx.x;
    const int wgid = (orig & 7) * 128 + (orig >> 3);
    const int m0 = (wgid & 15) * BM;
    const int n0 = (wgid >> 4) * BN;

    const int tid  = threadIdx.x;
    const int lane = tid & 63;
    const int w    = tid >> 6;
    const int wm   = w >> 1;            // 0..1 -> rows wm*64
    const int wn   = w & 1;             // 0..1 -> cols wn*80
    const int fr   = lane & 15;
    const int fkE  = (lane >> 4) * 8;

    const int trow  = tid >> 3;                        // staging row 0..31
    const int swcol = (((tid & 7) ^ (trow & 7))) * 8;  // pre-swizzled src col

    // stage unit = 32 rows x 64 cols fp16 = 4 KB = 256 thr x 16 B.
    // Global row = u*32 + trow; 32 % 8 == 0 keeps (row&7) == (trow&7),
    // so the read-side XOR matches the staged permutation.
    auto stage_a = [&](int b, int u, int kcol) {
        const _Float16* src = Ag + (size_t)(m0 + u * 32 + trow) * K + (kcol + swcol);
        __builtin_amdgcn_global_load_lds(
            (const __attribute__((address_space(1))) void*)src,
            (__attribute__((address_space(3))) void*)(AsF + b * AELE + u * 2048 + tid * 8),
            16, 0, 0);
    };
    auto stage_b = [&](int b, int u, int kcol) {
        const _Float16* src = Wg + (size_t)(n0 + u * 32 + trow) * K + (kcol + swcol);
        __builtin_amdgcn_global_load_lds(
            (const __attribute__((address_space(1))) void*)src,
            (__attribute__((address_space(3))) void*)(BsF + b * BELE + u * 2048 + tid * 8),
            16, 0, 0);
    };

    f32x4 acc[4][5];
#pragma unroll
    for (int i = 0; i < 4; ++i)
#pragma unroll
        for (int j = 0; j < 5; ++j)
            acc[i][j] = (f32x4){0.f, 0.f, 0.f, 0.f};

    // prologue: tile0 -> buf0 (9 loads), tile1 -> buf1 (9 loads)
#pragma unroll
    for (int u = 0; u < 4; ++u) stage_a(0, u, 0);
#pragma unroll
    for (int u = 0; u < 5; ++u) stage_b(0, u, 0);
#pragma unroll
    for (int u = 0; u < 4; ++u) stage_a(1, u, BK);
#pragma unroll
    for (int u = 0; u < 5; ++u) stage_b(1, u, BK);
    asm volatile("s_waitcnt vmcnt(9)" ::: "memory");   // tile0 landed
    BAR();

#pragma unroll 1
    for (int t = 0; t < NT; ++t) {
        const int cur = t & 1;
        const _Float16* Ab = AsF + cur * AELE;
        const _Float16* Bb = BsF + cur * BELE;
        const bool pf2 = (t + 2 < NT);
        const int k2 = (t + 2) * BK;

        half8 af[4][2], bf[5][2];

        // ---- P0: issue ALL 18 ds_reads (A first, then B)
#pragma unroll
        for (int rb = 0; rb < 4; ++rb)
#pragma unroll
            for (int kh = 0; kh < 2; ++kh)
                af[rb][kh] = lds_rd(Ab, wm * 64 + rb * 16 + fr, kh * 32 + fkE);
#pragma unroll
        for (int cb = 0; cb < 5; ++cb)
#pragma unroll
            for (int kh = 0; kh < 2; ++kh)
                bf[cb][kh] = lds_rd(Bb, wn * 80 + cb * 16 + fr, kh * 32 + fkE);

        // MFMA g1: A x Bcols{0,1,2} (24 MFMA) — late B reads drain under
        // these via compiler counted lgkm waits.
        __builtin_amdgcn_s_setprio(1);
#pragma unroll
        for (int rb = 0; rb < 4; ++rb)
#pragma unroll
            for (int cb = 0; cb < 3; ++cb)
#pragma unroll
                for (int kh = 0; kh < 2; ++kh)
                    acc[rb][cb] = __builtin_amdgcn_mfma_f32_16x16x32_f16(
                        af[rb][kh], bf[cb][kh], acc[rb][cb], 0, 0, 0);
        __builtin_amdgcn_s_setprio(0);

        LGKM0();   // all own reads complete (cross-wave safety for staging)
        BAR();     // -> every wave's reads of A(cur)+B(cur) are done

        // ---- P1: stage tile t+2 into cur (regions free); MFMA g2 (reg-only)
        if (pf2) {
#pragma unroll
            for (int u = 0; u < 4; ++u) stage_a(cur, u, k2);
#pragma unroll
            for (int u = 0; u < 5; ++u) stage_b(cur, u, k2);
        }
        __builtin_amdgcn_s_setprio(1);
#pragma unroll
        for (int rb = 0; rb < 4; ++rb)
#pragma unroll
            for (int cb = 3; cb < 5; ++cb)
#pragma unroll
                for (int kh = 0; kh < 2; ++kh)
                    acc[rb][cb] = __builtin_amdgcn_mfma_f32_16x16x32_f16(
                        af[rb][kh], bf[cb][kh], acc[rb][cb], 0, 0, 0);
        __builtin_amdgcn_s_setprio(0);

        if (pf2) asm volatile("s_waitcnt vmcnt(9)" ::: "memory");  // t+1 landed
        else     asm volatile("s_waitcnt vmcnt(0)" ::: "memory");  // tail drain
        BAR();   // publish t+1
    }

    // epilogue: C/D layout col = lane&15, row = (lane>>4)*4 + reg
    float bb[5];
#pragma unroll
    for (int j = 0; j < 5; ++j)
        bb[j] = bias[n0 + wn * 80 + j * 16 + fr];
#pragma unroll
    for (int i = 0; i < 4; ++i) {
        const int row = m0 + wm * 64 + i * 16 + (lane >> 4) * 4;
#pragma unroll
        for (int j = 0; j < 5; ++j) {
            const int col = n0 + wn * 80 + j * 16 + fr;
#pragma unroll
            for (int r = 0; r < 4; ++r)
                C[(size_t)(row + r) * N + col] =
                    (float)(_Float16)(acc[i][j][r] + bb[j]);
        }
    }
}

// ---------------------------------------------------------------------------
// Fallback (round-2 fused kernel, passing @434us) if ws too small.
__global__ __launch_bounds__(256, 2)
void qlinear_fused_kernel(const float* __restrict__ A, const float* __restrict__ W,
                          const float* __restrict__ Wsc, const float* __restrict__ bias,
                          float* __restrict__ C)
{
    __shared__ _Float16 As[128][64];
    __shared__ _Float16 Bs[128][64];

    const int nwg  = (M / 128) * (N / 128);
    const int orig = blockIdx.x;
    const int wgid = (orig & 7) * (nwg >> 3) + (orig >> 3);
    const int brow = wgid & (M / 128 - 1);
    const int bcol = wgid / (M / 128);
    const int m0 = brow * 128;
    const int n0 = bcol * 128;

    const int t    = threadIdx.x;
    const int lane = t & 63;
    const int wave = t >> 6;
    const int wr = (wave >> 1) * 64;
    const int wc = (wave & 1) * 64;
    const int fr = lane & 15;
    const int fk = (lane >> 4) * 8;
    const int srow = t >> 3;
    const int scol = (t & 7) * 8;

    _Float16 hs[4];
#pragma unroll
    for (int p = 0; p < 4; ++p)
        hs[p] = (_Float16)Wsc[n0 + srow + p * 32];

    f32x4 acc[4][4];
#pragma unroll
    for (int i = 0; i < 4; ++i)
#pragma unroll
        for (int j = 0; j < 4; ++j)
            acc[i][j] = (f32x4){0.f, 0.f, 0.f, 0.f};

    for (int k0 = 0; k0 < K; k0 += 64) {
        __syncthreads();
#pragma unroll
        for (int c = 0; c < 4; ++c) {
            const int rl = c * 32 + srow;
            const float* asrc = A + (size_t)(m0 + rl) * K + (k0 + scol);
            const float4 a0 = ((const float4*)asrc)[0];
            const float4 a1 = ((const float4*)asrc)[1];
            half8 av;
            av[0] = (_Float16)a0.x; av[1] = (_Float16)a0.y;
            av[2] = (_Float16)a0.z; av[3] = (_Float16)a0.w;
            av[4] = (_Float16)a1.x; av[5] = (_Float16)a1.y;
            av[6] = (_Float16)a1.z; av[7] = (_Float16)a1.w;
            *(half8*)&As[rl][scol] = av;
        }
#pragma unroll
        for (int p = 0; p < 4; ++p) {
            const int nl = srow + p * 32;
            const float* wsrc = W + (size_t)(n0 + nl) * K + (k0 + scol);
            const float4 w0 = ((const float4*)wsrc)[0];
            const float4 w1 = ((const float4*)wsrc)[1];
            half8 hv;
            hv[0] = (_Float16)w0.x * hs[p]; hv[1] = (_Float16)w0.y * hs[p];
            hv[2] = (_Float16)w0.z * hs[p]; hv[3] = (_Float16)w0.w * hs[p];
            hv[4] = (_Float16)w1.x * hs[p]; hv[5] = (_Float16)w1.y * hs[p];
            hv[6] = (_Float16)w1.z * hs[p]; hv[7] = (_Float16)w1.w * hs[p];
            *(half8*)&Bs[nl][scol] = hv;
        }
        __syncthreads();
#pragma unroll
        for (int kk = 0; kk < 64; kk += 32) {
            half8 av[4], bv[4];
#pragma unroll
            for (int i = 0; i < 4; ++i)
                av[i] = *(const half8*)&As[wr + i * 16 + fr][kk + fk];
#pragma unroll
            for (int j = 0; j < 4; ++j)
                bv[j] = *(const half8*)&Bs[wc + j * 16 + fr][kk + fk];
#pragma unroll
            for (int i = 0; i < 4; ++i)
#pragma unroll
                for (int j = 0; j < 4; ++j)
                    acc[i][j] = __builtin_amdgcn_mfma_f32_16x16x32_f16(
                        av[i], bv[j], acc[i][j], 0, 0, 0);
        }
    }
#pragma unroll
    for (int i = 0; i < 4; ++i) {
        const int row = m0 + wr + i * 16 + (lane >> 4) * 4;
#pragma unroll
        for (int j = 0; j < 4; ++j) {
            const int col = n0 + wc + j * 16 + fr;
            const float bbf = bias[col];
#pragma unroll
            for (int r = 0; r < 4; ++r)
                C[(size_t)(row + r) * N + col] =
                    (float)(_Float16)(acc[i][j][r] + bbf);
        }
    }
}

extern "C" void kernel_launch(void* const* d_in, const int* in_sizes, int n_in,
                              void* d_out, int out_size, void* d_ws, size_t ws_size,
                              hipStream_t stream) {
    const float* A    = (const float*)d_in[0];
    const float* W    = (const float*)d_in[1];
    const float* Wsc  = (const float*)d_in[2];
    const float* bias = (const float*)d_in[3];
    float* C = (float*)d_out;

    const size_t a_bytes = (size_t)M * K * sizeof(_Float16);   // 16.78 MB
    const size_t w_bytes = (size_t)N * K * sizeof(_Float16);   // 83.89 MB

    if (ws_size >= a_bytes + w_bytes) {
        _Float16* Ah = (_Float16*)d_ws;
        _Float16* Wh = (_Float16*)((char*)d_ws + a_bytes);
        convert_a_kernel<<<dim3(1024), dim3(256), 0, stream>>>(A, Ah);
        dequant_w_kernel<<<dim3(2048), dim3(256), 0, stream>>>(W, Wsc, Wh);
        const int nwg = (M / BM) * (N / BN);  // 1024
        qgemm128x160_kernel<<<dim3(nwg), dim3(256), 0, stream>>>(Ah, Wh, bias, C);
    } else {
        const int nwg = (M / 128) * (N / 128);
        qlinear_fused_kernel<<<dim3(nwg), dim3(256), 0, stream>>>(A, W, Wsc, bias, C);
    }
}

// Round 11
// 202.470 us; speedup vs baseline: 2.1438x; 1.0762x over previous
//
#include <hip/hip_runtime.h>
#include <hip/hip_fp16.h>

typedef _Float16 half8 __attribute__((ext_vector_type(8)));
typedef float f32x4 __attribute__((ext_vector_type(4)));

constexpr int M = 2048;    // B*S
constexpr int N = 10240;   // DOUT
constexpr int K = 4096;    // DIN

// ---------------------------------------------------------------------------
// Pre-pass 1: W fp32 -> fp16 * fp16(scale). Bit-identical to reference.
__global__ __launch_bounds__(256)
void dequant_w_kernel(const float* __restrict__ W, const float* __restrict__ Wsc,
                      _Float16* __restrict__ Wh) {
    const long total = (long)N * K / 8;
    for (long i = (long)blockIdx.x * blockDim.x + threadIdx.x; i < total;
         i += (long)gridDim.x * blockDim.x) {
        const long base = i * 8;
        const int row = (int)(base >> 12);           // / K
        const _Float16 s = (_Float16)Wsc[row];
        const float4 w0 = ((const float4*)(W + base))[0];
        const float4 w1 = ((const float4*)(W + base))[1];
        half8 h;
        h[0] = (_Float16)w0.x * s; h[1] = (_Float16)w0.y * s;
        h[2] = (_Float16)w0.z * s; h[3] = (_Float16)w0.w * s;
        h[4] = (_Float16)w1.x * s; h[5] = (_Float16)w1.y * s;
        h[6] = (_Float16)w1.z * s; h[7] = (_Float16)w1.w * s;
        *(half8*)(Wh + base) = h;
    }
}

// Pre-pass 2: A fp32 (fp16-valued) -> fp16 (exact).
__global__ __launch_bounds__(256)
void convert_a_kernel(const float* __restrict__ A, _Float16* __restrict__ Ah) {
    const long total = (long)M * K / 8;
    for (long i = (long)blockIdx.x * blockDim.x + threadIdx.x; i < total;
         i += (long)gridDim.x * blockDim.x) {
        const long base = i * 8;
        const float4 a0 = ((const float4*)(A + base))[0];
        const float4 a1 = ((const float4*)(A + base))[1];
        half8 h;
        h[0] = (_Float16)a0.x; h[1] = (_Float16)a0.y;
        h[2] = (_Float16)a0.z; h[3] = (_Float16)a0.w;
        h[4] = (_Float16)a1.x; h[5] = (_Float16)a1.y;
        h[6] = (_Float16)a1.z; h[7] = (_Float16)a1.w;
        *(half8*)(Ah + base) = h;
    }
}

// ---------------------------------------------------------------------------
// 256x320 GEMM: grid 8x32 = 256 blocks = 1 block/CU, ZERO tail.
// 8 waves (2M x 4N) of 128x80. kh-SPLIT 3-phase schedule: live operand set
// is one kh-slice (a[8]+b[5] = 52 VGPR) instead of both (104, round-8 spill).
// acc[8][5] = 160 AGPR; target ~250/256 unified regs -> 2 waves/SIMD.
//   P0: 13 ds_reads (kh0) -> 40 MFMA (all rb x cb, kh0)
//   P1: 13 ds_reads (kh1) -> 20 MFMA (rb 0..3, kh1); LGKM0+BAR (regions free)
//   P2: stage t+2 (9 gload_lds, distance-2) -> 20 MFMA (rb 4..7, kh1);
//       vmcnt(9) [t+1 landed, t+2 in flight]; BAR publishes t+1.
// T2 swizzle: linear gload_lds dest + pre-swizzled src col + swizzled read.
//
// Lifetime ledger: reads of buf cur all issued in P0/P1; LGKM0 before the
// P1-end BAR -> after it every wave's reads of A(cur)+B(cur) are complete,
// so staging t+2 into cur (P2) is safe. P2's MFMA is register-only.
// vmcnt(9) at P2 end: outstanding = t+2's 9 + t+1's 9 -> waits t+1's only.
// Tail (t+2>=NT): vmcnt(0).
constexpr int BM = 256, BN = 320, BK = 64;
constexpr int AELE = BM * BK;   // 16384 fp16 = 32 KB
constexpr int BELE = BN * BK;   // 20480 fp16 = 40 KB
constexpr int NT = K / BK;      // 64 K-tiles

#define BAR()   asm volatile("s_barrier" ::: "memory")
#define LGKM0() asm volatile("s_waitcnt lgkmcnt(0)" ::: "memory")

__device__ __forceinline__ half8 lds_rd(const _Float16* base, int row, int eo) {
    // T2: physical 16B slot = slot ^ (row&7)
    const int ps = (eo >> 3) ^ (row & 7);
    return *(const half8*)(base + row * BK + ps * 8);
}

__global__ __launch_bounds__(512, 2)
void qgemm256x320v2_kernel(const _Float16* __restrict__ Ag,  // [M,K] fp16 (ws)
                           const _Float16* __restrict__ Wg,  // [N,K] fp16 deq
                           const float*    __restrict__ bias,
                           float*          __restrict__ C)
{
    __shared__ _Float16 AsF[2 * AELE];   // 64 KB
    __shared__ _Float16 BsF[2 * BELE];   // 80 KB  (144 KB total)

    // XCD-bijective swizzle: 256 = 8 chunks x 32; brow-fast -> 8-block runs
    // share one 2.6MB B panel (L2-resident per XCD).
    const int orig = blockIdx.x;
    const int wgid = (orig & 7) * 32 + (orig >> 3);
    const int m0 = (wgid & 7) * BM;
    const int n0 = (wgid >> 3) * BN;

    const int tid  = threadIdx.x;
    const int lane = tid & 63;
    const int w    = tid >> 6;
    const int wm   = w >> 2;            // 0..1 -> rows wm*128
    const int wn   = w & 3;             // 0..3 -> cols wn*80
    const int fr   = lane & 15;
    const int fkE  = (lane >> 4) * 8;

    const int trow  = tid >> 3;                        // staging row 0..63
    const int swcol = (((tid & 7) ^ (trow & 7))) * 8;  // pre-swizzled src col

    // stage unit = 64 rows x 64 cols fp16 = 8 KB = 512 thr x 16 B
    auto stage_a = [&](int b, int u, int kcol) {
        const _Float16* src = Ag + (size_t)(m0 + u * 64 + trow) * K + (kcol + swcol);
        __builtin_amdgcn_global_load_lds(
            (const __attribute__((address_space(1))) void*)src,
            (__attribute__((address_space(3))) void*)(AsF + b * AELE + u * 4096 + tid * 8),
            16, 0, 0);
    };
    auto stage_b = [&](int b, int u, int kcol) {
        const _Float16* src = Wg + (size_t)(n0 + u * 64 + trow) * K + (kcol + swcol);
        __builtin_amdgcn_global_load_lds(
            (const __attribute__((address_space(1))) void*)src,
            (__attribute__((address_space(3))) void*)(BsF + b * BELE + u * 4096 + tid * 8),
            16, 0, 0);
    };

    f32x4 acc[8][5];
#pragma unroll
    for (int i = 0; i < 8; ++i)
#pragma unroll
        for (int j = 0; j < 5; ++j)
            acc[i][j] = (f32x4){0.f, 0.f, 0.f, 0.f};

    // prologue: tile0 -> buf0 (9 loads), tile1 -> buf1 (9 loads)
#pragma unroll
    for (int u = 0; u < 4; ++u) stage_a(0, u, 0);
#pragma unroll
    for (int u = 0; u < 5; ++u) stage_b(0, u, 0);
#pragma unroll
    for (int u = 0; u < 4; ++u) stage_a(1, u, BK);
#pragma unroll
    for (int u = 0; u < 5; ++u) stage_b(1, u, BK);
    asm volatile("s_waitcnt vmcnt(9)" ::: "memory");   // tile0 landed
    BAR();

    const int rowA = wm * 128 + fr;     // A fragment row base
    const int rowB = wn * 80 + fr;      // B fragment row base

#pragma unroll 1
    for (int t = 0; t < NT; ++t) {
        const int cur = t & 1;
        const _Float16* Ab = AsF + cur * AELE;
        const _Float16* Bb = BsF + cur * BELE;
        const bool pf2 = (t + 2 < NT);
        const int k2 = (t + 2) * BK;

        // ---- P0: kh=0 reads (13), then 40 MFMA (all rb x cb, kh0).
        {
            half8 a0[8], b0[5];
#pragma unroll
            for (int rb = 0; rb < 8; ++rb)
                a0[rb] = lds_rd(Ab, rowA + rb * 16, fkE);
#pragma unroll
            for (int cb = 0; cb < 5; ++cb)
                b0[cb] = lds_rd(Bb, rowB + cb * 16, fkE);
            __builtin_amdgcn_s_setprio(1);
#pragma unroll
            for (int rb = 0; rb < 8; ++rb)
#pragma unroll
                for (int cb = 0; cb < 5; ++cb)
                    acc[rb][cb] = __builtin_amdgcn_mfma_f32_16x16x32_f16(
                        a0[rb], b0[cb], acc[rb][cb], 0, 0, 0);
            __builtin_amdgcn_s_setprio(0);
        }

        // ---- P1: kh=1 reads (13), 20 MFMA (rb 0..3); LGKM0+BAR frees bufs.
        half8 a1[8], b1[5];
#pragma unroll
        for (int rb = 0; rb < 8; ++rb)
            a1[rb] = lds_rd(Ab, rowA + rb * 16, 32 + fkE);
#pragma unroll
        for (int cb = 0; cb < 5; ++cb)
            b1[cb] = lds_rd(Bb, rowB + cb * 16, 32 + fkE);
        __builtin_amdgcn_s_setprio(1);
#pragma unroll
        for (int rb = 0; rb < 4; ++rb)
#pragma unroll
            for (int cb = 0; cb < 5; ++cb)
                acc[rb][cb] = __builtin_amdgcn_mfma_f32_16x16x32_f16(
                    a1[rb], b1[cb], acc[rb][cb], 0, 0, 0);
        __builtin_amdgcn_s_setprio(0);
        LGKM0();   // all own reads of cur complete (cross-wave stage safety)
        BAR();     // every wave done reading A(cur)+B(cur)

        // ---- P2: stage t+2 into cur; 20 MFMA (rb 4..7, reg-only); vmcnt.
        if (pf2) {
#pragma unroll
            for (int u = 0; u < 4; ++u) stage_a(cur, u, k2);
#pragma unroll
            for (int u = 0; u < 5; ++u) stage_b(cur, u, k2);
        }
        __builtin_amdgcn_s_setprio(1);
#pragma unroll
        for (int rb = 4; rb < 8; ++rb)
#pragma unroll
            for (int cb = 0; cb < 5; ++cb)
                acc[rb][cb] = __builtin_amdgcn_mfma_f32_16x16x32_f16(
                    a1[rb], b1[cb], acc[rb][cb], 0, 0, 0);
        __builtin_amdgcn_s_setprio(0);
        if (pf2) asm volatile("s_waitcnt vmcnt(9)" ::: "memory");  // t+1 landed
        else     asm volatile("s_waitcnt vmcnt(0)" ::: "memory");  // tail drain
        BAR();   // publish t+1
    }

    // epilogue: C/D layout col = lane&15, row = (lane>>4)*4 + reg
    float bb[5];
#pragma unroll
    for (int j = 0; j < 5; ++j)
        bb[j] = bias[n0 + wn * 80 + j * 16 + fr];
#pragma unroll
    for (int i = 0; i < 8; ++i) {
        const int row = m0 + wm * 128 + i * 16 + (lane >> 4) * 4;
#pragma unroll
        for (int j = 0; j < 5; ++j) {
            const int col = n0 + wn * 80 + j * 16 + fr;
#pragma unroll
            for (int r = 0; r < 4; ++r)
                C[(size_t)(row + r) * N + col] =
                    (float)(_Float16)(acc[i][j][r] + bb[j]);
        }
    }
}

// ---------------------------------------------------------------------------
// Fallback (round-2 fused kernel, passing @434us) if ws too small.
__global__ __launch_bounds__(256, 2)
void qlinear_fused_kernel(const float* __restrict__ A, const float* __restrict__ W,
                          const float* __restrict__ Wsc, const float* __restrict__ bias,
                          float* __restrict__ C)
{
    __shared__ _Float16 As[128][64];
    __shared__ _Float16 Bs[128][64];

    const int nwg  = (M / 128) * (N / 128);
    const int orig = blockIdx.x;
    const int wgid = (orig & 7) * (nwg >> 3) + (orig >> 3);
    const int brow = wgid & (M / 128 - 1);
    const int bcol = wgid / (M / 128);
    const int m0 = brow * 128;
    const int n0 = bcol * 128;

    const int t    = threadIdx.x;
    const int lane = t & 63;
    const int wave = t >> 6;
    const int wr = (wave >> 1) * 64;
    const int wc = (wave & 1) * 64;
    const int fr = lane & 15;
    const int fk = (lane >> 4) * 8;
    const int srow = t >> 3;
    const int scol = (t & 7) * 8;

    _Float16 hs[4];
#pragma unroll
    for (int p = 0; p < 4; ++p)
        hs[p] = (_Float16)Wsc[n0 + srow + p * 32];

    f32x4 acc[4][4];
#pragma unroll
    for (int i = 0; i < 4; ++i)
#pragma unroll
        for (int j = 0; j < 4; ++j)
            acc[i][j] = (f32x4){0.f, 0.f, 0.f, 0.f};

    for (int k0 = 0; k0 < K; k0 += 64) {
        __syncthreads();
#pragma unroll
        for (int c = 0; c < 4; ++c) {
            const int rl = c * 32 + srow;
            const float* asrc = A + (size_t)(m0 + rl) * K + (k0 + scol);
            const float4 a0 = ((const float4*)asrc)[0];
            const float4 a1 = ((const float4*)asrc)[1];
            half8 av;
            av[0] = (_Float16)a0.x; av[1] = (_Float16)a0.y;
            av[2] = (_Float16)a0.z; av[3] = (_Float16)a0.w;
            av[4] = (_Float16)a1.x; av[5] = (_Float16)a1.y;
            av[6] = (_Float16)a1.z; av[7] = (_Float16)a1.w;
            *(half8*)&As[rl][scol] = av;
        }
#pragma unroll
        for (int p = 0; p < 4; ++p) {
            const int nl = srow + p * 32;
            const float* wsrc = W + (size_t)(n0 + nl) * K + (k0 + scol);
            const float4 w0 = ((const float4*)wsrc)[0];
            const float4 w1 = ((const float4*)wsrc)[1];
            half8 hv;
            hv[0] = (_Float16)w0.x * hs[p]; hv[1] = (_Float16)w0.y * hs[p];
            hv[2] = (_Float16)w0.z * hs[p]; hv[3] = (_Float16)w0.w * hs[p];
            hv[4] = (_Float16)w1.x * hs[p]; hv[5] = (_Float16)w1.y * hs[p];
            hv[6] = (_Float16)w1.z * hs[p]; hv[7] = (_Float16)w1.w * hs[p];
            *(half8*)&Bs[nl][scol] = hv;
        }
        __syncthreads();
#pragma unroll
        for (int kk = 0; kk < 64; kk += 32) {
            half8 av[4], bv[4];
#pragma unroll
            for (int i = 0; i < 4; ++i)
                av[i] = *(const half8*)&As[wr + i * 16 + fr][kk + fk];
#pragma unroll
            for (int j = 0; j < 4; ++j)
                bv[j] = *(const half8*)&Bs[wc + j * 16 + fr][kk + fk];
#pragma unroll
            for (int i = 0; i < 4; ++i)
#pragma unroll
                for (int j = 0; j < 4; ++j)
                    acc[i][j] = __builtin_amdgcn_mfma_f32_16x16x32_f16(
                        av[i], bv[j], acc[i][j], 0, 0, 0);
        }
    }
#pragma unroll
    for (int i = 0; i < 4; ++i) {
        const int row = m0 + wr + i * 16 + (lane >> 4) * 4;
#pragma unroll
        for (int j = 0; j < 4; ++j) {
            const int col = n0 + wc + j * 16 + fr;
            const float bbf = bias[col];
#pragma unroll
            for (int r = 0; r < 4; ++r)
                C[(size_t)(row + r) * N + col] =
                    (float)(_Float16)(acc[i][j][r] + bbf);
        }
    }
}

extern "C" void kernel_launch(void* const* d_in, const int* in_sizes, int n_in,
                              void* d_out, int out_size, void* d_ws, size_t ws_size,
                              hipStream_t stream) {
    const float* A    = (const float*)d_in[0];
    const float* W    = (const float*)d_in[1];
    const float* Wsc  = (const float*)d_in[2];
    const float* bias = (const float*)d_in[3];
    float* C = (float*)d_out;

    const size_t a_bytes = (size_t)M * K * sizeof(_Float16);   // 16.78 MB
    const size_t w_bytes = (size_t)N * K * sizeof(_Float16);   // 83.89 MB

    if (ws_size >= a_bytes + w_bytes) {
        _Float16* Ah = (_Float16*)d_ws;
        _Float16* Wh = (_Float16*)((char*)d_ws + a_bytes);
        convert_a_kernel<<<dim3(1024), dim3(256), 0, stream>>>(A, Ah);
        dequant_w_kernel<<<dim3(2048), dim3(256), 0, stream>>>(W, Wsc, Wh);
        const int nwg = (M / BM) * (N / BN);  // 256
        qgemm256x320v2_kernel<<<dim3(nwg), dim3(512), 0, stream>>>(Ah, Wh, bias, C);
    } else {
        const int nwg = (M / 128) * (N / 128);
        qlinear_fused_kernel<<<dim3(nwg), dim3(256), 0, stream>>>(A, W, Wsc, bias, C);
    }
}